// Round 6
// baseline (1752.804 us; speedup 1.0000x reference)
//
#include <hip/hip_runtime.h>
#include <math.h>
#include <float.h>

#define N_NODES 1024
#define IN_CH   1433
#define HID     16
#define OUT_CH  7
#define N_EDGES 4096
#define E_TOT   5120   // N_EDGES + N_NODES (self loops)
#define N_TE    5119   // E_TOT - 1 (embedded series length)
#define N_TEP   5120   // pitch for per-rank arrays
#define NBUCK   1024
#define IB      20     // ceil(N_TE / 256)
#define PAD     64     // sentinel pad on each side of staged arrays
#define BPC     32     // blocks per channel in te_walk
#define BIGF    1e30f

__device__ __forceinline__ int src_of(const int* ei, int t) {
    return (t < N_EDGES) ? ei[t] : t - N_EDGES;
}
__device__ __forceinline__ int dst_of(const int* ei, int t) {
    return (t < N_EDGES) ? ei[N_EDGES + t] : t - N_EDGES;
}

// psi(x) for integer-valued x >= 0. Recurrence to x>=6 then asymptotic.
__device__ __forceinline__ float digammaf_dev(float x) {
    float r = 0.0f;
    while (x < 6.0f) { r -= 1.0f / x; x += 1.0f; }
    float inv  = 1.0f / x;
    float inv2 = inv * inv;
    r += logf(x) - 0.5f * inv
       - inv2 * (1.0f/12.0f - inv2 * (1.0f/120.0f - inv2 * (1.0f/252.0f)));
    return r;
}

__global__ __launch_bounds__(256) void gemm1_kernel(
    const float* __restrict__ x, const float* __restrict__ W1,
    const float* __restrict__ b1, float* __restrict__ h1) {
    __shared__ float xrow[IN_CH];
    const int r = blockIdx.x;
    const float* xr = x + (size_t)r * IN_CH;
    for (int k = threadIdx.x; k < IN_CH; k += 256) xrow[k] = xr[k];
    __syncthreads();
    const int o = threadIdx.x >> 4;
    const int g = threadIdx.x & 15;
    const float* wp = W1 + o * IN_CH;
    float s = 0.0f;
    for (int k = g; k < IN_CH; k += 16) s += xrow[k] * wp[k];
    #pragma unroll
    for (int m = 8; m >= 1; m >>= 1) s += __shfl_xor(s, m, 16);
    if (g == 0) h1[r * HID + o] = s + b1[o];
}

__global__ void cnt_kernel(const int* __restrict__ ei, float* __restrict__ cnt) {
    int e = blockIdx.x * blockDim.x + threadIdx.x;
    if (e >= E_TOT) return;
    atomicAdd(&cnt[dst_of(ei, e)], 1.0f);
}

// Bucket scatter: approx y-order (monotone across buckets, arbitrary within).
__global__ __launch_bounds__(1024) void sortA_kernel(
    const float* __restrict__ h, const int* __restrict__ ei, int C,
    float* __restrict__ ys_tmp, int* __restrict__ idx_tmp,
    int* __restrict__ bstart, float* __restrict__ meta) {
    const int c = blockIdx.x;
    const int tid = threadIdx.x;
    __shared__ unsigned int hist[NBUCK];
    __shared__ float wmn[16], wmx[16];
    __shared__ float s_lo, s_sc;
    float mn = BIGF, mx = -BIGF;
    for (int t = tid; t < N_TE; t += 1024) {
        float v = h[src_of(ei, t) * C + c];
        mn = fminf(mn, v); mx = fmaxf(mx, v);
    }
    #pragma unroll
    for (int m = 32; m >= 1; m >>= 1) {
        mn = fminf(mn, __shfl_xor(mn, m, 64));
        mx = fmaxf(mx, __shfl_xor(mx, m, 64));
    }
    if ((tid & 63) == 0) { wmn[tid >> 6] = mn; wmx[tid >> 6] = mx; }
    hist[tid] = 0u;
    __syncthreads();
    if (tid == 0) {
        float a = wmn[0], b = wmx[0];
        for (int k = 1; k < 16; ++k) { a = fminf(a, wmn[k]); b = fmaxf(b, wmx[k]); }
        s_lo = a;
        s_sc = (b > a) ? (float)(NBUCK - 1) / (b - a) : 0.0f;
        meta[2 * c] = a; meta[2 * c + 1] = s_sc;
    }
    __syncthreads();
    const float lo = s_lo, sc = s_sc;
    for (int t = tid; t < N_TE; t += 1024) {
        float v = h[src_of(ei, t) * C + c];
        int b = min(max((int)((v - lo) * sc), 0), NBUCK - 1);
        atomicAdd(&hist[b], 1u);
    }
    __syncthreads();
    for (int off = 1; off < NBUCK; off <<= 1) {   // inclusive scan
        unsigned v = hist[tid];
        unsigned add = (tid >= off) ? hist[tid - off] : 0u;
        __syncthreads();
        hist[tid] = v + add;
        __syncthreads();
    }
    unsigned excl = (tid > 0) ? hist[tid - 1] : 0u;
    __syncthreads();
    hist[tid] = excl;
    bstart[c * (NBUCK + 1) + tid] = (int)excl;
    if (tid == 0) bstart[c * (NBUCK + 1) + NBUCK] = N_TE;
    __syncthreads();
    for (int t = tid; t < N_TE; t += 1024) {
        float v = h[src_of(ei, t) * C + c];
        int b = min(max((int)((v - lo) * sc), 0), NBUCK - 1);
        unsigned r = atomicAdd(&hist[b], 1u);
        ys_tmp[c * N_TEP + r] = v;
        idx_tmp[c * N_TEP + r] = t;
    }
}

// Exact refine: rank within bucket by (y, orig idx); emit sorted y and
// gathered x (=h[dst_t]) and z (=h[src_{t+1}]) payloads as separate arrays.
__global__ __launch_bounds__(256) void sortB_kernel(
    const float* __restrict__ h, const int* __restrict__ ei, int C,
    const float* __restrict__ ys_tmp, const int* __restrict__ idx_tmp,
    const int* __restrict__ bstart, const float* __restrict__ meta,
    float* __restrict__ ys_s, float* __restrict__ xs_s, float* __restrict__ zs_s) {
    const int c = blockIdx.y;
    const int r = blockIdx.x * 256 + threadIdx.x;
    if (r >= N_TE) return;
    const float y = ys_tmp[c * N_TEP + r];
    const int t = idx_tmp[c * N_TEP + r];
    const float lo = meta[2 * c], sc = meta[2 * c + 1];
    int b = min(max((int)((y - lo) * sc), 0), NBUCK - 1);
    const int s = bstart[c * (NBUCK + 1) + b];
    const int e = bstart[c * (NBUCK + 1) + b + 1];
    int cnt = 0;
    for (int q = s; q < e; ++q) {
        float yq = ys_tmp[c * N_TEP + q];
        int tq = idx_tmp[c * N_TEP + q];
        cnt += (yq < y || (yq == y && tq < t)) ? 1 : 0;
    }
    const int pos = s + cnt;
    ys_s[c * N_TEP + pos] = y;
    xs_s[c * N_TEP + pos] = h[dst_of(ei, t) * C + c];
    zs_s[c * N_TEP + pos] = h[src_of(ei, t + 1) * C + c];
}

// Wave-cooperative KSG TE over y-sorted arrays, dynamic point-stealing.
// One wave (64 lanes) per point: batched eps expansion + exact binary-search
// window + ballot counts. grid = (BPC * C) blocks x 1024 threads.
__global__ __launch_bounds__(1024) void te_walk_kernel(
    const float* __restrict__ ys_s, const float* __restrict__ xs_s,
    const float* __restrict__ zs_s, int bpc,
    int* __restrict__ ctr, float* __restrict__ tes) {
    __shared__ float sy[N_TEP + 2 * PAD];
    __shared__ float sx[N_TEP + 2 * PAD];
    __shared__ float sz[N_TEP + 2 * PAD];
    const int c = blockIdx.x / bpc;
    for (int t = threadIdx.x; t < N_TEP + 2 * PAD; t += 1024) {
        int q = t - PAD;
        bool in = (q >= 0 && q < N_TE);
        sy[t] = in ? ys_s[c * N_TEP + q] : ((q < 0) ? -BIGF : BIGF);
        sx[t] = in ? xs_s[c * N_TEP + q] : BIGF;
        sz[t] = in ? zs_s[c * N_TEP + q] : BIGF;
    }
    __syncthreads();

    const int lane = threadIdx.x & 63;
    float acc = 0.0f;
    for (int steal = 0; steal < N_TE; ++steal) {   // hard bound (belt & braces)
        int p0 = 0;
        if (lane == 0) p0 = atomicAdd(&ctr[c], 1);
        const int p = __shfl(p0, 0, 64);
        if (p >= N_TE) break;

        const float yi = sy[PAD + p];
        const float xi = sx[PAD + p];
        const float zi = sz[PAD + p];

        // ---- eps: seed batch [p-32, p+32), then expand right/left ----
        float e;
        {
            int q = p - 32 + lane;
            float dy = fabsf(yi - sy[PAD + q]);
            float d = fmaxf(dy, fmaxf(fabsf(xi - sx[PAD + q]), fabsf(zi - sz[PAD + q])));
            if (q == p) d = BIGF;
            #pragma unroll
            for (int m = 32; m >= 1; m >>= 1) d = fminf(d, __shfl_xor(d, m, 64));
            e = d;
        }
        int r = p + 32, l = p - 32;
        for (int iter = 0; iter < 2 * (N_TE / 64 + 2); ++iter) {  // structurally bounded
            bool go_r = (r < N_TE) && (sy[PAD + r] - yi < e);
            bool go_l = (l > 0) && (yi - sy[PAD + l - 1] < e);
            if (!go_r && !go_l) break;
            if (go_r) {
                int q = r + lane;
                float d = fmaxf(sy[PAD + q] - yi,
                                fmaxf(fabsf(xi - sx[PAD + q]), fabsf(zi - sz[PAD + q])));
                #pragma unroll
                for (int m = 32; m >= 1; m >>= 1) d = fminf(d, __shfl_xor(d, m, 64));
                e = fminf(e, d);
                r += 64;
            }
            if (go_l) {
                int q = l - 64 + lane;
                float d = fmaxf(yi - sy[PAD + q],
                                fmaxf(fabsf(xi - sx[PAD + q]), fabsf(zi - sz[PAD + q])));
                #pragma unroll
                for (int m = 32; m >= 1; m >>= 1) d = fminf(d, __shfl_xor(d, m, 64));
                e = fminf(e, d);
                l -= 64;
            }
        }

        // ---- window [lo, hi): ranks with rounded |dy| < eps (monotone -> exact) ----
        int wlo, whi;
        if (e > 0.0f) {
            int a = 0, b = p;                      // pred(p) = (0 < e) = true
            while (a < b) {
                int m = (a + b) >> 1;
                if (fabsf(yi - sy[PAD + m]) < e) b = m; else a = m + 1;
            }
            wlo = a;
            a = p + 1; b = N_TE;                   // first q with |dy| >= e
            while (a < b) {
                int m = (a + b) >> 1;
                if (fabsf(yi - sy[PAD + m]) >= e) b = m; else a = m + 1;
            }
            whi = a;
        } else { wlo = 0; whi = 0; }

        // ---- counts (diagonal included: cancels +1 in psi(n+1)) ----
        int ny = whi - wlo;
        int nxy = 0, nyz = 0;
        for (int base = wlo; base < whi; base += 64) {
            int q = base + lane;
            bool valid = q < whi;
            bool bx = valid && (fabsf(xi - sx[PAD + q]) < e);
            bool bz = valid && (fabsf(zi - sz[PAD + q]) < e);
            nxy += (int)__popcll(__ballot(bx));
            nyz += (int)__popcll(__ballot(bz));
        }
        acc += digammaf_dev((float)ny) - digammaf_dev((float)nxy)
             - digammaf_dev((float)nyz);
    }
    if (lane == 0 && acc != 0.0f) atomicAdd(&tes[c], acc);
}

template <int C>
__global__ void agg_kernel(const float* __restrict__ h, const int* __restrict__ ei,
                           const float* __restrict__ tes_accum, float half_scale,
                           float* __restrict__ sums) {
    int idx = blockIdx.x * blockDim.x + threadIdx.x;
    if (idx >= E_TOT * C) return;
    int e = idx / C, c = idx % C;
    float te = (-0.57721566490153286f + tes_accum[c] * (1.0f / (float)N_TE)) * half_scale;
    float xj = h[src_of(ei, e) * C + c];
    float m = 1.0f / (1.0f + expf(-te * xj));
    atomicAdd(&sums[dst_of(ei, e) * C + c], m);
}

__global__ void fin1_kernel(const float* __restrict__ sums, const float* __restrict__ cnt,
                            float* __restrict__ h1a) {
    int idx = blockIdx.x * blockDim.x + threadIdx.x;
    if (idx >= N_NODES * HID) return;
    int v = idx / HID;
    float val = sums[idx] / fmaxf(cnt[v], 1.0f);
    h1a[idx] = fmaxf(val, 0.0f);
}

__global__ void gemm2_kernel(const float* __restrict__ h1a, const float* __restrict__ W2,
                             const float* __restrict__ b2, float* __restrict__ h2) {
    int idx = blockIdx.x * blockDim.x + threadIdx.x;
    if (idx >= N_NODES * OUT_CH) return;
    int v = idx / OUT_CH, o = idx % OUT_CH;
    float s = b2[o];
    #pragma unroll
    for (int k = 0; k < HID; ++k) s += h1a[v * HID + k] * W2[o * HID + k];
    h2[idx] = s;
}

__global__ void fin2_kernel(const float* __restrict__ sums2, const float* __restrict__ cnt,
                            float* __restrict__ out) {
    int v = blockIdx.x * blockDim.x + threadIdx.x;
    if (v >= N_NODES) return;
    float c = fmaxf(cnt[v], 1.0f);
    float vals[OUT_CH];
    float mx = -INFINITY;
    #pragma unroll
    for (int o = 0; o < OUT_CH; ++o) {
        vals[o] = sums2[v * OUT_CH + o] / c;
        mx = fmaxf(mx, vals[o]);
    }
    float se = 0.0f;
    #pragma unroll
    for (int o = 0; o < OUT_CH; ++o) se += expf(vals[o] - mx);
    float lse = mx + logf(se);
    #pragma unroll
    for (int o = 0; o < OUT_CH; ++o) out[v * OUT_CH + o] = vals[o] - lse;
}

extern "C" void kernel_launch(void* const* d_in, const int* in_sizes, int n_in,
                              void* d_out, int out_size, void* d_ws, size_t ws_size,
                              hipStream_t stream) {
    const float* x  = (const float*)d_in[0];
    const int*   ei = (const int*)  d_in[1];
    const float* W1 = (const float*)d_in[2];
    const float* b1 = (const float*)d_in[3];
    const float* W2 = (const float*)d_in[4];
    const float* b2 = (const float*)d_in[5];
    float* out = (float*)d_out;

    float* w = (float*)d_ws;
    size_t o = 0;
    // ---- zeroed region (atomic accumulators + work counters) ----
    float* sums1 = w + o; o += N_NODES * HID;
    float* sums2 = w + o; o += N_NODES * OUT_CH;
    float* cdeg  = w + o; o += N_NODES;
    float* tes1  = w + o; o += 16;
    float* tes2  = w + o; o += 16;
    int* ctr1 = (int*)(w + o); o += 16;
    int* ctr2 = (int*)(w + o); o += 16;
    const size_t zero_elems = o;
    // ---- non-zeroed region (sort buffers shared between layers) ----
    float* h1      = w + o; o += N_NODES * HID;
    float* h1a     = w + o; o += N_NODES * HID;
    float* h2      = w + o; o += N_NODES * OUT_CH;
    float* ys_tmp  = w + o; o += HID * N_TEP;
    int*   idx_tmp = (int*)(w + o); o += HID * N_TEP;
    float* ys_srt  = w + o; o += HID * N_TEP;
    float* xs_srt  = w + o; o += HID * N_TEP;
    float* zs_srt  = w + o; o += HID * N_TEP;
    int*   bstart  = (int*)(w + o); o += HID * (NBUCK + 1);
    float* meta    = w + o; o += 2 * HID;

    hipMemsetAsync(d_ws, 0, zero_elems * sizeof(float), stream);

    gemm1_kernel<<<N_NODES, 256, 0, stream>>>(x, W1, b1, h1);
    cnt_kernel<<<(E_TOT + 255) / 256, 256, 0, stream>>>(ei, cdeg);

    // ---- layer 1 ----
    sortA_kernel<<<HID, 1024, 0, stream>>>(h1, ei, HID, ys_tmp, idx_tmp, bstart, meta);
    sortB_kernel<<<dim3(IB, HID), 256, 0, stream>>>(h1, ei, HID, ys_tmp, idx_tmp,
                                                    bstart, meta, ys_srt, xs_srt, zs_srt);
    te_walk_kernel<<<BPC * HID, 1024, 0, stream>>>(ys_srt, xs_srt, zs_srt, BPC, ctr1, tes1);
    agg_kernel<HID><<<(E_TOT * HID + 255) / 256, 256, 0, stream>>>(h1, ei, tes1, 1.0f, sums1);
    fin1_kernel<<<(N_NODES * HID + 255) / 256, 256, 0, stream>>>(sums1, cdeg, h1a);

    // ---- layer 2 ----
    gemm2_kernel<<<(N_NODES * OUT_CH + 255) / 256, 256, 0, stream>>>(h1a, W2, b2, h2);
    sortA_kernel<<<OUT_CH, 1024, 0, stream>>>(h2, ei, OUT_CH, ys_tmp, idx_tmp, bstart, meta);
    sortB_kernel<<<dim3(IB, OUT_CH), 256, 0, stream>>>(h2, ei, OUT_CH, ys_tmp, idx_tmp,
                                                       bstart, meta, ys_srt, xs_srt, zs_srt);
    te_walk_kernel<<<BPC * OUT_CH, 1024, 0, stream>>>(ys_srt, xs_srt, zs_srt, BPC, ctr2, tes2);
    agg_kernel<OUT_CH><<<(E_TOT * OUT_CH + 255) / 256, 256, 0, stream>>>(h2, ei, tes2, 0.5f, sums2);
    fin2_kernel<<<(N_NODES + 255) / 256, 256, 0, stream>>>(sums2, cdeg, out);
}

// Round 7
// 794.548 us; speedup vs baseline: 2.2060x; 2.2060x over previous
//
#include <hip/hip_runtime.h>
#include <math.h>
#include <float.h>

#define N_NODES 1024
#define IN_CH   1433
#define HID     16
#define OUT_CH  7
#define N_EDGES 4096
#define E_TOT   5120   // N_EDGES + N_NODES (self loops)
#define N_TE    5119   // E_TOT - 1 (embedded series length)
#define N_TEP   5120   // pitch for per-rank arrays
#define NBUCK   1024
#define IB      20     // ceil(N_TE / 256)
#define PAD2    128    // sentinel pad each side of staged arrays
#define SEQS    5376   // N_TE + 2*PAD2 rounded up to x4 (5375 -> 5376)
#define BIGF    1e30f

__device__ __forceinline__ int src_of(const int* ei, int t) {
    return (t < N_EDGES) ? ei[t] : t - N_EDGES;
}
__device__ __forceinline__ int dst_of(const int* ei, int t) {
    return (t < N_EDGES) ? ei[N_EDGES + t] : t - N_EDGES;
}

// psi(x) for integer-valued x >= 1. Recurrence to x>=6 then asymptotic.
__device__ __forceinline__ float digammaf_dev(float x) {
    float r = 0.0f;
    while (x < 6.0f) { r -= 1.0f / x; x += 1.0f; }
    float inv  = 1.0f / x;
    float inv2 = inv * inv;
    r += logf(x) - 0.5f * inv
       - inv2 * (1.0f/12.0f - inv2 * (1.0f/120.0f - inv2 * (1.0f/252.0f)));
    return r;
}

__global__ __launch_bounds__(256) void gemm1_kernel(
    const float* __restrict__ x, const float* __restrict__ W1,
    const float* __restrict__ b1, float* __restrict__ h1) {
    __shared__ float xrow[IN_CH];
    const int r = blockIdx.x;
    const float* xr = x + (size_t)r * IN_CH;
    for (int k = threadIdx.x; k < IN_CH; k += 256) xrow[k] = xr[k];
    __syncthreads();
    const int o = threadIdx.x >> 4;
    const int g = threadIdx.x & 15;
    const float* wp = W1 + o * IN_CH;
    float s = 0.0f;
    for (int k = g; k < IN_CH; k += 16) s += xrow[k] * wp[k];
    #pragma unroll
    for (int m = 8; m >= 1; m >>= 1) s += __shfl_xor(s, m, 16);
    if (g == 0) h1[r * HID + o] = s + b1[o];
}

__global__ void cnt_kernel(const int* __restrict__ ei, float* __restrict__ cnt) {
    int e = blockIdx.x * blockDim.x + threadIdx.x;
    if (e >= E_TOT) return;
    atomicAdd(&cnt[dst_of(ei, e)], 1.0f);
}

// Bucket scatter: approx y-order (monotone across buckets, arbitrary within).
__global__ __launch_bounds__(1024) void sortA_kernel(
    const float* __restrict__ h, const int* __restrict__ ei, int C,
    float* __restrict__ ys_tmp, int* __restrict__ idx_tmp,
    int* __restrict__ bstart, float* __restrict__ meta) {
    const int c = blockIdx.x;
    const int tid = threadIdx.x;
    __shared__ unsigned int hist[NBUCK];
    __shared__ float wmn[16], wmx[16];
    __shared__ float s_lo, s_sc;
    float mn = BIGF, mx = -BIGF;
    for (int t = tid; t < N_TE; t += 1024) {
        float v = h[src_of(ei, t) * C + c];
        mn = fminf(mn, v); mx = fmaxf(mx, v);
    }
    #pragma unroll
    for (int m = 32; m >= 1; m >>= 1) {
        mn = fminf(mn, __shfl_xor(mn, m, 64));
        mx = fmaxf(mx, __shfl_xor(mx, m, 64));
    }
    if ((tid & 63) == 0) { wmn[tid >> 6] = mn; wmx[tid >> 6] = mx; }
    hist[tid] = 0u;
    __syncthreads();
    if (tid == 0) {
        float a = wmn[0], b = wmx[0];
        for (int k = 1; k < 16; ++k) { a = fminf(a, wmn[k]); b = fmaxf(b, wmx[k]); }
        s_lo = a;
        s_sc = (b > a) ? (float)(NBUCK - 1) / (b - a) : 0.0f;
        meta[2 * c] = a; meta[2 * c + 1] = s_sc;
    }
    __syncthreads();
    const float lo = s_lo, sc = s_sc;
    for (int t = tid; t < N_TE; t += 1024) {
        float v = h[src_of(ei, t) * C + c];
        int b = min(max((int)((v - lo) * sc), 0), NBUCK - 1);
        atomicAdd(&hist[b], 1u);
    }
    __syncthreads();
    for (int off = 1; off < NBUCK; off <<= 1) {   // inclusive scan
        unsigned v = hist[tid];
        unsigned add = (tid >= off) ? hist[tid - off] : 0u;
        __syncthreads();
        hist[tid] = v + add;
        __syncthreads();
    }
    unsigned excl = (tid > 0) ? hist[tid - 1] : 0u;
    __syncthreads();
    hist[tid] = excl;
    bstart[c * (NBUCK + 1) + tid] = (int)excl;
    if (tid == 0) bstart[c * (NBUCK + 1) + NBUCK] = N_TE;
    __syncthreads();
    for (int t = tid; t < N_TE; t += 1024) {
        float v = h[src_of(ei, t) * C + c];
        int b = min(max((int)((v - lo) * sc), 0), NBUCK - 1);
        unsigned r = atomicAdd(&hist[b], 1u);
        ys_tmp[c * N_TEP + r] = v;
        idx_tmp[c * N_TEP + r] = t;
    }
}

// Exact refine: rank within bucket by (y, orig idx); emit sorted y and
// gathered x (=h[dst_t]) and z (=h[src_{t+1}]) payloads.
__global__ __launch_bounds__(256) void sortB_kernel(
    const float* __restrict__ h, const int* __restrict__ ei, int C,
    const float* __restrict__ ys_tmp, const int* __restrict__ idx_tmp,
    const int* __restrict__ bstart, const float* __restrict__ meta,
    float* __restrict__ ys_s, float* __restrict__ xs_s, float* __restrict__ zs_s) {
    const int c = blockIdx.y;
    const int r = blockIdx.x * 256 + threadIdx.x;
    if (r >= N_TE) return;
    const float y = ys_tmp[c * N_TEP + r];
    const int t = idx_tmp[c * N_TEP + r];
    const float lo = meta[2 * c], sc = meta[2 * c + 1];
    int b = min(max((int)((y - lo) * sc), 0), NBUCK - 1);
    const int s = bstart[c * (NBUCK + 1) + b];
    const int e = bstart[c * (NBUCK + 1) + b + 1];
    int cnt = 0;
    for (int q = s; q < e; ++q) {
        float yq = ys_tmp[c * N_TEP + q];
        int tq = idx_tmp[c * N_TEP + q];
        cnt += (yq < y || (yq == y && tq < t)) ? 1 : 0;
    }
    const int pos = s + cnt;
    ys_s[c * N_TEP + pos] = y;
    xs_s[c * N_TEP + pos] = h[dst_of(ei, t) * C + c];
    zs_s[c * N_TEP + pos] = h[src_of(ei, t + 1) * C + c];
}

// Banded KSG TE over y-sorted arrays. Lane owns rank p = wave_base + lane;
// the wave scans one contiguous band with wave-uniform chunk bounds (__any
// frontier tests once per 64-j chunk); inner loops are dense float4 broadcast
// reads + predicated per-lane math (R2 shape). Exact: sorted y => dy monotone
// in rank; stop conditions conservative; min/max/abs/cmp are rounding-free.
// grid = (IB, C), block = 256 (4 waves).
__global__ __launch_bounds__(256) void te_band_kernel(
    const float* __restrict__ ys_s, const float* __restrict__ xs_s,
    const float* __restrict__ zs_s, float* __restrict__ tes) {
    __shared__ float sy[SEQS];
    __shared__ float sx[SEQS];
    __shared__ float sz[SEQS];
    __shared__ float wsum[4];
    const int c = blockIdx.y;
    for (int t = threadIdx.x; t < SEQS; t += 256) {
        int q = t - PAD2;
        bool in = (q >= 0 && q < N_TE);
        sy[t] = in ? ys_s[c * N_TEP + q] : ((q < 0) ? -BIGF : BIGF);
        sx[t] = in ? xs_s[c * N_TEP + q] : BIGF;
        sz[t] = in ? zs_s[c * N_TEP + q] : BIGF;
    }
    __syncthreads();

    const int lane = threadIdx.x & 63;
    const int w0 = blockIdx.x * 256 + (threadIdx.x & ~63);  // wave rank base
    int p = w0 + lane;
    const bool active = (p < N_TE);
    if (!active) p = N_TE - 1;
    const float yi = sy[PAD2 + p];
    const float xi = sx[PAD2 + p];
    const float zi = sz[PAD2 + p];

    // ---- pass A: eps (1-NN Chebyshev dist, diagonal excluded) ----
    float e = BIGF;
    // seed [w0-64, w0+128): contains every lane's p; diagonal check needed here only
    for (int jb = w0 - 64; jb < w0 + 128; jb += 4) {
        float4 y4 = *(const float4*)(sy + PAD2 + jb);
        float4 x4 = *(const float4*)(sx + PAD2 + jb);
        float4 z4 = *(const float4*)(sz + PAD2 + jb);
        float d0 = fmaxf(fabsf(y4.x - yi), fmaxf(fabsf(x4.x - xi), fabsf(z4.x - zi)));
        float d1 = fmaxf(fabsf(y4.y - yi), fmaxf(fabsf(x4.y - xi), fabsf(z4.y - zi)));
        float d2 = fmaxf(fabsf(y4.z - yi), fmaxf(fabsf(x4.z - xi), fabsf(z4.z - zi)));
        float d3 = fmaxf(fabsf(y4.w - yi), fmaxf(fabsf(x4.w - xi), fabsf(z4.w - zi)));
        d0 = (jb     == p) ? BIGF : d0;
        d1 = (jb + 1 == p) ? BIGF : d1;
        d2 = (jb + 2 == p) ? BIGF : d2;
        d3 = (jb + 3 == p) ? BIGF : d3;
        e = fminf(e, fminf(fminf(d0, d1), fminf(d2, d3)));
    }
    // right expansion (chunks of 64; no diagonal possible)
    for (int r = w0 + 128; r < N_TE; r += 64) {
        if (!__any(sy[PAD2 + r] - yi < e)) break;
        for (int jb = r; jb < r + 64; jb += 4) {
            float4 y4 = *(const float4*)(sy + PAD2 + jb);
            float4 x4 = *(const float4*)(sx + PAD2 + jb);
            float4 z4 = *(const float4*)(sz + PAD2 + jb);
            float d0 = fmaxf(y4.x - yi, fmaxf(fabsf(x4.x - xi), fabsf(z4.x - zi)));
            float d1 = fmaxf(y4.y - yi, fmaxf(fabsf(x4.y - xi), fabsf(z4.y - zi)));
            float d2 = fmaxf(y4.z - yi, fmaxf(fabsf(x4.z - xi), fabsf(z4.z - zi)));
            float d3 = fmaxf(y4.w - yi, fmaxf(fabsf(x4.w - xi), fabsf(z4.w - zi)));
            e = fminf(e, fminf(fminf(d0, d1), fminf(d2, d3)));
        }
    }
    // left expansion
    for (int l = w0 - 64; l > 0; l -= 64) {
        if (!__any(yi - sy[PAD2 + l - 1] < e)) break;
        for (int jb = l - 64; jb < l; jb += 4) {
            float4 y4 = *(const float4*)(sy + PAD2 + jb);
            float4 x4 = *(const float4*)(sx + PAD2 + jb);
            float4 z4 = *(const float4*)(sz + PAD2 + jb);
            float d0 = fmaxf(yi - y4.x, fmaxf(fabsf(x4.x - xi), fabsf(z4.x - zi)));
            float d1 = fmaxf(yi - y4.y, fmaxf(fabsf(x4.y - xi), fabsf(z4.y - zi)));
            float d2 = fmaxf(yi - y4.z, fmaxf(fabsf(x4.z - xi), fabsf(z4.z - zi)));
            float d3 = fmaxf(yi - y4.w, fmaxf(fabsf(x4.w - xi), fabsf(z4.w - zi)));
            e = fminf(e, fminf(fminf(d0, d1), fminf(d2, d3)));
        }
    }

    // ---- pass B: counts with |.|<eps (diagonal included: the +1 of psi(n+1)) ----
    int ny = 0, nxy = 0, nyz = 0;
    // own region [w0, w0+64)
    for (int jb = w0; jb < w0 + 64; jb += 4) {
        float4 y4 = *(const float4*)(sy + PAD2 + jb);
        float4 x4 = *(const float4*)(sx + PAD2 + jb);
        float4 z4 = *(const float4*)(sz + PAD2 + jb);
        int b0 = fabsf(y4.x - yi) < e, b1 = fabsf(y4.y - yi) < e;
        int b2 = fabsf(y4.z - yi) < e, b3 = fabsf(y4.w - yi) < e;
        ny  += b0 + b1 + b2 + b3;
        nxy += (b0 & (int)(fabsf(x4.x - xi) < e)) + (b1 & (int)(fabsf(x4.y - xi) < e))
             + (b2 & (int)(fabsf(x4.z - xi) < e)) + (b3 & (int)(fabsf(x4.w - xi) < e));
        nyz += (b0 & (int)(fabsf(z4.x - zi) < e)) + (b1 & (int)(fabsf(z4.y - zi) < e))
             + (b2 & (int)(fabsf(z4.z - zi) < e)) + (b3 & (int)(fabsf(z4.w - zi) < e));
    }
    for (int r = w0 + 64; r < N_TE; r += 64) {
        if (!__any(sy[PAD2 + r] - yi < e)) break;
        for (int jb = r; jb < r + 64; jb += 4) {
            float4 y4 = *(const float4*)(sy + PAD2 + jb);
            float4 x4 = *(const float4*)(sx + PAD2 + jb);
            float4 z4 = *(const float4*)(sz + PAD2 + jb);
            int b0 = (y4.x - yi) < e, b1 = (y4.y - yi) < e;
            int b2 = (y4.z - yi) < e, b3 = (y4.w - yi) < e;
            ny  += b0 + b1 + b2 + b3;
            nxy += (b0 & (int)(fabsf(x4.x - xi) < e)) + (b1 & (int)(fabsf(x4.y - xi) < e))
                 + (b2 & (int)(fabsf(x4.z - xi) < e)) + (b3 & (int)(fabsf(x4.w - xi) < e));
            nyz += (b0 & (int)(fabsf(z4.x - zi) < e)) + (b1 & (int)(fabsf(z4.y - zi) < e))
                 + (b2 & (int)(fabsf(z4.z - zi) < e)) + (b3 & (int)(fabsf(z4.w - zi) < e));
        }
    }
    for (int l = w0; l > 0; l -= 64) {
        if (!__any(yi - sy[PAD2 + l - 1] < e)) break;
        for (int jb = l - 64; jb < l; jb += 4) {
            float4 y4 = *(const float4*)(sy + PAD2 + jb);
            float4 x4 = *(const float4*)(sx + PAD2 + jb);
            float4 z4 = *(const float4*)(sz + PAD2 + jb);
            int b0 = (yi - y4.x) < e, b1 = (yi - y4.y) < e;
            int b2 = (yi - y4.z) < e, b3 = (yi - y4.w) < e;
            ny  += b0 + b1 + b2 + b3;
            nxy += (b0 & (int)(fabsf(x4.x - xi) < e)) + (b1 & (int)(fabsf(x4.y - xi) < e))
                 + (b2 & (int)(fabsf(x4.z - xi) < e)) + (b3 & (int)(fabsf(x4.w - xi) < e));
            nyz += (b0 & (int)(fabsf(z4.x - zi) < e)) + (b1 & (int)(fabsf(z4.y - zi) < e))
                 + (b2 & (int)(fabsf(z4.z - zi) < e)) + (b3 & (int)(fabsf(z4.w - zi) < e));
        }
    }

    float local = active ? (digammaf_dev((float)ny) - digammaf_dev((float)nxy)
                          - digammaf_dev((float)nyz)) : 0.0f;
    #pragma unroll
    for (int m = 32; m >= 1; m >>= 1) local += __shfl_xor(local, m, 64);
    if ((threadIdx.x & 63) == 0) wsum[threadIdx.x >> 6] = local;
    __syncthreads();
    if (threadIdx.x == 0)
        atomicAdd(&tes[c], wsum[0] + wsum[1] + wsum[2] + wsum[3]);
}

template <int C>
__global__ void agg_kernel(const float* __restrict__ h, const int* __restrict__ ei,
                           const float* __restrict__ tes_accum, float half_scale,
                           float* __restrict__ sums) {
    int idx = blockIdx.x * blockDim.x + threadIdx.x;
    if (idx >= E_TOT * C) return;
    int e = idx / C, c = idx % C;
    float te = (-0.57721566490153286f + tes_accum[c] * (1.0f / (float)N_TE)) * half_scale;
    float xj = h[src_of(ei, e) * C + c];
    float m = 1.0f / (1.0f + expf(-te * xj));
    atomicAdd(&sums[dst_of(ei, e) * C + c], m);
}

__global__ void fin1_kernel(const float* __restrict__ sums, const float* __restrict__ cnt,
                            float* __restrict__ h1a) {
    int idx = blockIdx.x * blockDim.x + threadIdx.x;
    if (idx >= N_NODES * HID) return;
    int v = idx / HID;
    float val = sums[idx] / fmaxf(cnt[v], 1.0f);
    h1a[idx] = fmaxf(val, 0.0f);
}

__global__ void gemm2_kernel(const float* __restrict__ h1a, const float* __restrict__ W2,
                             const float* __restrict__ b2, float* __restrict__ h2) {
    int idx = blockIdx.x * blockDim.x + threadIdx.x;
    if (idx >= N_NODES * OUT_CH) return;
    int v = idx / OUT_CH, o = idx % OUT_CH;
    float s = b2[o];
    #pragma unroll
    for (int k = 0; k < HID; ++k) s += h1a[v * HID + k] * W2[o * HID + k];
    h2[idx] = s;
}

__global__ void fin2_kernel(const float* __restrict__ sums2, const float* __restrict__ cnt,
                            float* __restrict__ out) {
    int v = blockIdx.x * blockDim.x + threadIdx.x;
    if (v >= N_NODES) return;
    float c = fmaxf(cnt[v], 1.0f);
    float vals[OUT_CH];
    float mx = -INFINITY;
    #pragma unroll
    for (int o = 0; o < OUT_CH; ++o) {
        vals[o] = sums2[v * OUT_CH + o] / c;
        mx = fmaxf(mx, vals[o]);
    }
    float se = 0.0f;
    #pragma unroll
    for (int o = 0; o < OUT_CH; ++o) se += expf(vals[o] - mx);
    float lse = mx + logf(se);
    #pragma unroll
    for (int o = 0; o < OUT_CH; ++o) out[v * OUT_CH + o] = vals[o] - lse;
}

extern "C" void kernel_launch(void* const* d_in, const int* in_sizes, int n_in,
                              void* d_out, int out_size, void* d_ws, size_t ws_size,
                              hipStream_t stream) {
    const float* x  = (const float*)d_in[0];
    const int*   ei = (const int*)  d_in[1];
    const float* W1 = (const float*)d_in[2];
    const float* b1 = (const float*)d_in[3];
    const float* W2 = (const float*)d_in[4];
    const float* b2 = (const float*)d_in[5];
    float* out = (float*)d_out;

    float* w = (float*)d_ws;
    size_t o = 0;
    // ---- zeroed region (atomic accumulators) ----
    float* sums1 = w + o; o += N_NODES * HID;
    float* sums2 = w + o; o += N_NODES * OUT_CH;
    float* cdeg  = w + o; o += N_NODES;
    float* tes1  = w + o; o += 16;
    float* tes2  = w + o; o += 16;
    const size_t zero_elems = o;
    // ---- non-zeroed region (sort buffers shared between layers) ----
    float* h1      = w + o; o += N_NODES * HID;
    float* h1a     = w + o; o += N_NODES * HID;
    float* h2      = w + o; o += N_NODES * OUT_CH;
    float* ys_tmp  = w + o; o += HID * N_TEP;
    int*   idx_tmp = (int*)(w + o); o += HID * N_TEP;
    float* ys_srt  = w + o; o += HID * N_TEP;
    float* xs_srt  = w + o; o += HID * N_TEP;
    float* zs_srt  = w + o; o += HID * N_TEP;
    int*   bstart  = (int*)(w + o); o += HID * (NBUCK + 1);
    float* meta    = w + o; o += 2 * HID;

    hipMemsetAsync(d_ws, 0, zero_elems * sizeof(float), stream);

    gemm1_kernel<<<N_NODES, 256, 0, stream>>>(x, W1, b1, h1);
    cnt_kernel<<<(E_TOT + 255) / 256, 256, 0, stream>>>(ei, cdeg);

    // ---- layer 1 ----
    sortA_kernel<<<HID, 1024, 0, stream>>>(h1, ei, HID, ys_tmp, idx_tmp, bstart, meta);
    sortB_kernel<<<dim3(IB, HID), 256, 0, stream>>>(h1, ei, HID, ys_tmp, idx_tmp,
                                                    bstart, meta, ys_srt, xs_srt, zs_srt);
    te_band_kernel<<<dim3(IB, HID), 256, 0, stream>>>(ys_srt, xs_srt, zs_srt, tes1);
    agg_kernel<HID><<<(E_TOT * HID + 255) / 256, 256, 0, stream>>>(h1, ei, tes1, 1.0f, sums1);
    fin1_kernel<<<(N_NODES * HID + 255) / 256, 256, 0, stream>>>(sums1, cdeg, h1a);

    // ---- layer 2 ----
    gemm2_kernel<<<(N_NODES * OUT_CH + 255) / 256, 256, 0, stream>>>(h1a, W2, b2, h2);
    sortA_kernel<<<OUT_CH, 1024, 0, stream>>>(h2, ei, OUT_CH, ys_tmp, idx_tmp, bstart, meta);
    sortB_kernel<<<dim3(IB, OUT_CH), 256, 0, stream>>>(h2, ei, OUT_CH, ys_tmp, idx_tmp,
                                                       bstart, meta, ys_srt, xs_srt, zs_srt);
    te_band_kernel<<<dim3(IB, OUT_CH), 256, 0, stream>>>(ys_srt, xs_srt, zs_srt, tes2);
    agg_kernel<OUT_CH><<<(E_TOT * OUT_CH + 255) / 256, 256, 0, stream>>>(h2, ei, tes2, 0.5f, sums2);
    fin2_kernel<<<(N_NODES + 255) / 256, 256, 0, stream>>>(sums2, cdeg, out);
}

// Round 9
// 408.020 us; speedup vs baseline: 4.2959x; 1.9473x over previous
//
#include <hip/hip_runtime.h>
#include <math.h>
#include <float.h>

#define N_NODES 1024
#define IN_CH   1433
#define HID     16
#define OUT_CH  7
#define N_EDGES 4096
#define E_TOT   5120   // N_EDGES + N_NODES (self loops)
#define N_TE    5119   // E_TOT - 1 (embedded points, ranks 0..5118)
#define N_TEP   5120   // pitch; slot 5119 holds BIGF sentinel
#define NBUCK   1024
#define CHUNK   512    // j-chunk per tile
#define NCH     10
#define IBS     256    // i-block size
#define IB      20
#define BIGF    1e30f

__device__ __forceinline__ int src_of(const int* ei, int t) {
    return (t < N_EDGES) ? ei[t] : t - N_EDGES;
}
__device__ __forceinline__ int dst_of(const int* ei, int t) {
    return (t < N_EDGES) ? ei[N_EDGES + t] : t - N_EDGES;
}

// psi(x) for integer-valued x >= 1. Recurrence to x>=6 then asymptotic.
__device__ __forceinline__ float digammaf_dev(float x) {
    float r = 0.0f;
    while (x < 6.0f) { r -= 1.0f / x; x += 1.0f; }
    float inv  = 1.0f / x;
    float inv2 = inv * inv;
    r += logf(x) - 0.5f * inv
       - inv2 * (1.0f/12.0f - inv2 * (1.0f/120.0f - inv2 * (1.0f/252.0f)));
    return r;
}

__global__ __launch_bounds__(256) void gemm1_kernel(
    const float* __restrict__ x, const float* __restrict__ W1,
    const float* __restrict__ b1, float* __restrict__ h1) {
    __shared__ float xrow[IN_CH];
    const int r = blockIdx.x;
    const float* xr = x + (size_t)r * IN_CH;
    for (int k = threadIdx.x; k < IN_CH; k += 256) xrow[k] = xr[k];
    __syncthreads();
    const int o = threadIdx.x >> 4;
    const int g = threadIdx.x & 15;
    const float* wp = W1 + o * IN_CH;
    float s = 0.0f;
    for (int k = g; k < IN_CH; k += 16) s += xrow[k] * wp[k];
    #pragma unroll
    for (int m = 8; m >= 1; m >>= 1) s += __shfl_xor(s, m, 16);
    if (g == 0) h1[r * HID + o] = s + b1[o];
}

__global__ void deg_kernel(const int* __restrict__ ei, float* __restrict__ cnt) {
    int e = blockIdx.x * blockDim.x + threadIdx.x;
    if (e >= E_TOT) return;
    atomicAdd(&cnt[dst_of(ei, e)], 1.0f);
}

// Bucket scatter: approx y-order (monotone across buckets, arbitrary within).
__global__ __launch_bounds__(1024) void sortA_kernel(
    const float* __restrict__ h, const int* __restrict__ ei, int C,
    float* __restrict__ ys_tmp, int* __restrict__ idx_tmp,
    int* __restrict__ bstart, float* __restrict__ meta) {
    const int c = blockIdx.x;
    const int tid = threadIdx.x;
    __shared__ unsigned int hist[NBUCK];
    __shared__ float wmn[16], wmx[16];
    __shared__ float s_lo, s_sc;
    float mn = BIGF, mx = -BIGF;
    for (int t = tid; t < N_TE; t += 1024) {
        float v = h[src_of(ei, t) * C + c];
        mn = fminf(mn, v); mx = fmaxf(mx, v);
    }
    #pragma unroll
    for (int m = 32; m >= 1; m >>= 1) {
        mn = fminf(mn, __shfl_xor(mn, m, 64));
        mx = fmaxf(mx, __shfl_xor(mx, m, 64));
    }
    if ((tid & 63) == 0) { wmn[tid >> 6] = mn; wmx[tid >> 6] = mx; }
    hist[tid] = 0u;
    __syncthreads();
    if (tid == 0) {
        float a = wmn[0], b = wmx[0];
        for (int k = 1; k < 16; ++k) { a = fminf(a, wmn[k]); b = fmaxf(b, wmx[k]); }
        s_lo = a;
        s_sc = (b > a) ? (float)(NBUCK - 1) / (b - a) : 0.0f;
        meta[2 * c] = a; meta[2 * c + 1] = s_sc;
    }
    __syncthreads();
    const float lo = s_lo, sc = s_sc;
    for (int t = tid; t < N_TE; t += 1024) {
        float v = h[src_of(ei, t) * C + c];
        int b = min(max((int)((v - lo) * sc), 0), NBUCK - 1);
        atomicAdd(&hist[b], 1u);
    }
    __syncthreads();
    for (int off = 1; off < NBUCK; off <<= 1) {   // inclusive scan
        unsigned v = hist[tid];
        unsigned add = (tid >= off) ? hist[tid - off] : 0u;
        __syncthreads();
        hist[tid] = v + add;
        __syncthreads();
    }
    unsigned excl = (tid > 0) ? hist[tid - 1] : 0u;
    __syncthreads();
    hist[tid] = excl;
    bstart[c * (NBUCK + 1) + tid] = (int)excl;
    if (tid == 0) bstart[c * (NBUCK + 1) + NBUCK] = N_TE;
    __syncthreads();
    for (int t = tid; t < N_TE; t += 1024) {
        float v = h[src_of(ei, t) * C + c];
        int b = min(max((int)((v - lo) * sc), 0), NBUCK - 1);
        unsigned r = atomicAdd(&hist[b], 1u);
        ys_tmp[c * N_TEP + r] = v;
        idx_tmp[c * N_TEP + r] = t;
    }
}

// Exact refine: rank within bucket by (y, orig idx); emit sorted y + payloads.
__global__ __launch_bounds__(256) void sortB_kernel(
    const float* __restrict__ h, const int* __restrict__ ei, int C,
    const float* __restrict__ ys_tmp, const int* __restrict__ idx_tmp,
    const int* __restrict__ bstart, const float* __restrict__ meta,
    float* __restrict__ ys_s, float* __restrict__ xs_s, float* __restrict__ zs_s) {
    const int c = blockIdx.y;
    if (blockIdx.x == 0 && threadIdx.x == 0) {    // sentinel in pad slot
        ys_s[c * N_TEP + N_TE] = BIGF;
        xs_s[c * N_TEP + N_TE] = BIGF;
        zs_s[c * N_TEP + N_TE] = BIGF;
    }
    const int r = blockIdx.x * 256 + threadIdx.x;
    if (r >= N_TE) return;
    const float y = ys_tmp[c * N_TEP + r];
    const int t = idx_tmp[c * N_TEP + r];
    const float lo = meta[2 * c], sc = meta[2 * c + 1];
    int b = min(max((int)((y - lo) * sc), 0), NBUCK - 1);
    const int s = bstart[c * (NBUCK + 1) + b];
    const int e = bstart[c * (NBUCK + 1) + b + 1];
    int cnt = 0;
    for (int q = s; q < e; ++q) {
        float yq = ys_tmp[c * N_TEP + q];
        int tq = idx_tmp[c * N_TEP + q];
        cnt += (yq < y || (yq == y && tq < t)) ? 1 : 0;
    }
    const int pos = s + cnt;
    ys_s[c * N_TEP + pos] = y;
    xs_s[c * N_TEP + pos] = h[dst_of(ei, t) * C + c];
    zs_s[c * N_TEP + pos] = h[src_of(ei, t + 1) * C + c];
}

// eps upper bound from +-32 rank neighbors; also per-i-block max -> Mub.
// Any j with d_j = eps has |dy| <= eps <= eps_ub, so the eps_ub window
// provably contains the argmin. grid = (IB, C).
__global__ __launch_bounds__(256) void epsub_kernel(
    const float* __restrict__ ys_s, const float* __restrict__ xs_s,
    const float* __restrict__ zs_s, unsigned int* __restrict__ eps_u,
    float* __restrict__ Mub) {
    __shared__ float sy[IBS + 64], sx[IBS + 64], sz[IBS + 64];
    __shared__ float wred[4];
    const int c = blockIdx.y, ib = blockIdx.x;
    const int base = ib * IBS - 32;
    for (int t = threadIdx.x; t < IBS + 64; t += 256) {
        int q = base + t;
        bool in = (q >= 0 && q < N_TE);
        sy[t] = in ? ys_s[c * N_TEP + q] : BIGF;
        sx[t] = in ? xs_s[c * N_TEP + q] : BIGF;
        sz[t] = in ? zs_s[c * N_TEP + q] : BIGF;
    }
    __syncthreads();
    const int p = ib * IBS + threadIdx.x;
    const int l = threadIdx.x + 32;
    float e = BIGF;
    if (p < N_TE) {
        const float yi = sy[l], xi = sx[l], zi = sz[l];
        #pragma unroll 4
        for (int o = 1; o <= 32; ++o) {
            float d1 = fmaxf(fabsf(sy[l+o]-yi), fmaxf(fabsf(sx[l+o]-xi), fabsf(sz[l+o]-zi)));
            float d2 = fmaxf(fabsf(sy[l-o]-yi), fmaxf(fabsf(sx[l-o]-xi), fabsf(sz[l-o]-zi)));
            e = fminf(e, fminf(d1, d2));
        }
        eps_u[c * N_TEP + p] = __float_as_uint(e);
    }
    float em = (p < N_TE) ? e : 0.0f;
    #pragma unroll
    for (int m = 32; m >= 1; m >>= 1) em = fmaxf(em, __shfl_xor(em, m, 64));
    if ((threadIdx.x & 63) == 0) wred[threadIdx.x >> 6] = em;
    __syncthreads();
    if (threadIdx.x == 0)
        Mub[c * IB + ib] = fmaxf(fmaxf(wred[0], wred[1]), fmaxf(wred[2], wred[3]));
}

// block-uniform tile inclusion: chunk y-interval vs i-block interval +- M
__device__ __forceinline__ bool tile_hit(const float* __restrict__ ys,
                                         int c, int ib, int k, float Mv) {
    float ylo = ys[c * N_TEP + ib * IBS];
    float yhi = ys[c * N_TEP + min(ib * IBS + IBS - 1, N_TE - 1)];
    float clo = ys[c * N_TEP + k * CHUNK];
    float chi = ys[c * N_TEP + min(k * CHUNK + CHUNK - 1, N_TE - 1)];
    float M2 = Mv + fabsf(Mv) * 4e-7f;
    float hiB = yhi + M2; hiB += fabsf(hiB) * 4e-7f + 1e-37f;
    float loB = ylo - M2; loB -= fabsf(loB) * 4e-7f + 1e-37f;
    return (clo <= hiB) && (chi >= loB);
}

// eps tiles: R2-dense scan, pruned by tile_hit. grid = (IB, NCH, C).
__global__ __launch_bounds__(256) void te_eps_kernel(
    const float* __restrict__ ys_s, const float* __restrict__ xs_s,
    const float* __restrict__ zs_s, const float* __restrict__ Mub,
    unsigned int* __restrict__ eps_u) {
    const int ib = blockIdx.x, k = blockIdx.y, c = blockIdx.z;
    if (!tile_hit(ys_s, c, ib, k, Mub[c * IB + ib])) return;
    __shared__ __align__(16) float sy[CHUNK], sx[CHUNK], sz[CHUNK];
    const int j0 = k * CHUNK;
    for (int t = threadIdx.x; t < CHUNK; t += 256) {
        sy[t] = ys_s[c * N_TEP + j0 + t];
        sx[t] = xs_s[c * N_TEP + j0 + t];
        sz[t] = zs_s[c * N_TEP + j0 + t];
    }
    __syncthreads();
    const int p = ib * IBS + threadIdx.x;
    const float yi = ys_s[c * N_TEP + p];
    const float xi = xs_s[c * N_TEP + p];
    const float zi = zs_s[c * N_TEP + p];
    float e = BIGF;
    if (k == (ib >> 1)) {   // this tile contains each thread's diagonal
        for (int jg = 0; jg < CHUNK; jg += 4) {
            float4 y4 = *(const float4*)(sy + jg);
            float4 x4 = *(const float4*)(sx + jg);
            float4 z4 = *(const float4*)(sz + jg);
            float d0 = fmaxf(fabsf(y4.x - yi), fmaxf(fabsf(x4.x - xi), fabsf(z4.x - zi)));
            float d1 = fmaxf(fabsf(y4.y - yi), fmaxf(fabsf(x4.y - xi), fabsf(z4.y - zi)));
            float d2 = fmaxf(fabsf(y4.z - yi), fmaxf(fabsf(x4.z - xi), fabsf(z4.z - zi)));
            float d3 = fmaxf(fabsf(y4.w - yi), fmaxf(fabsf(x4.w - xi), fabsf(z4.w - zi)));
            int jb = j0 + jg;
            if ((unsigned)(p - jb) < 4u) {
                d0 = (jb     == p) ? BIGF : d0;
                d1 = (jb + 1 == p) ? BIGF : d1;
                d2 = (jb + 2 == p) ? BIGF : d2;
                d3 = (jb + 3 == p) ? BIGF : d3;
            }
            e = fminf(e, fminf(fminf(d0, d1), fminf(d2, d3)));
        }
    } else {
        #pragma unroll 2
        for (int jg = 0; jg < CHUNK; jg += 4) {
            float4 y4 = *(const float4*)(sy + jg);
            float4 x4 = *(const float4*)(sx + jg);
            float4 z4 = *(const float4*)(sz + jg);
            float d0 = fmaxf(fabsf(y4.x - yi), fmaxf(fabsf(x4.x - xi), fabsf(z4.x - zi)));
            float d1 = fmaxf(fabsf(y4.y - yi), fmaxf(fabsf(x4.y - xi), fabsf(z4.y - zi)));
            float d2 = fmaxf(fabsf(y4.z - yi), fmaxf(fabsf(x4.z - xi), fabsf(z4.z - zi)));
            float d3 = fmaxf(fabsf(y4.w - yi), fmaxf(fabsf(x4.w - xi), fabsf(z4.w - zi)));
            e = fminf(e, fminf(fminf(d0, d1), fminf(d2, d3)));
        }
    }
    if (p < N_TE)
        atomicMin(&eps_u[c * N_TEP + p], __float_as_uint(e));
}

// per-i-block max of final eps -> M2 (tighter cnt-tile pruning). grid (IB, C)
__global__ __launch_bounds__(256) void blockmax_kernel(
    const unsigned int* __restrict__ eps_u, float* __restrict__ M2) {
    __shared__ float wred[4];
    const int c = blockIdx.y, ib = blockIdx.x;
    const int p = ib * IBS + threadIdx.x;
    float e = (p < N_TE) ? __uint_as_float(eps_u[c * N_TEP + p]) : 0.0f;
    #pragma unroll
    for (int m = 32; m >= 1; m >>= 1) e = fmaxf(e, __shfl_xor(e, m, 64));
    if ((threadIdx.x & 63) == 0) wred[threadIdx.x >> 6] = e;
    __syncthreads();
    if (threadIdx.x == 0)
        M2[c * IB + ib] = fmaxf(fmaxf(wred[0], wred[1]), fmaxf(wred[2], wred[3]));
}

// cnt tiles: strict-< counts, diagonal included (supplies +1 of psi(n+1)).
// grid = (IB, NCH, C).
__global__ __launch_bounds__(256) void te_cnt_kernel(
    const float* __restrict__ ys_s, const float* __restrict__ xs_s,
    const float* __restrict__ zs_s, const float* __restrict__ M2,
    const unsigned int* __restrict__ eps_u, int* __restrict__ cntY,
    int* __restrict__ cntXY, int* __restrict__ cntYZ) {
    const int ib = blockIdx.x, k = blockIdx.y, c = blockIdx.z;
    if (!tile_hit(ys_s, c, ib, k, M2[c * IB + ib])) return;
    __shared__ __align__(16) float sy[CHUNK], sx[CHUNK], sz[CHUNK];
    const int j0 = k * CHUNK;
    for (int t = threadIdx.x; t < CHUNK; t += 256) {
        sy[t] = ys_s[c * N_TEP + j0 + t];
        sx[t] = xs_s[c * N_TEP + j0 + t];
        sz[t] = zs_s[c * N_TEP + j0 + t];
    }
    __syncthreads();
    const int p = ib * IBS + threadIdx.x;
    const float yi = ys_s[c * N_TEP + p];
    const float xi = xs_s[c * N_TEP + p];
    const float zi = zs_s[c * N_TEP + p];
    const float epsi = (p < N_TE) ? __uint_as_float(eps_u[c * N_TEP + p]) : 0.0f;
    int ny = 0, nxy = 0, nyz = 0;
    #pragma unroll 2
    for (int jg = 0; jg < CHUNK; jg += 4) {
        float4 y4 = *(const float4*)(sy + jg);
        float4 x4 = *(const float4*)(sx + jg);
        float4 z4 = *(const float4*)(sz + jg);
        int b0 = fabsf(y4.x - yi) < epsi, b1 = fabsf(y4.y - yi) < epsi;
        int b2 = fabsf(y4.z - yi) < epsi, b3 = fabsf(y4.w - yi) < epsi;
        ny  += b0 + b1 + b2 + b3;
        nxy += (b0 & (int)(fabsf(x4.x - xi) < epsi)) + (b1 & (int)(fabsf(x4.y - xi) < epsi))
             + (b2 & (int)(fabsf(x4.z - xi) < epsi)) + (b3 & (int)(fabsf(x4.w - xi) < epsi));
        nyz += (b0 & (int)(fabsf(z4.x - zi) < epsi)) + (b1 & (int)(fabsf(z4.y - zi) < epsi))
             + (b2 & (int)(fabsf(z4.z - zi) < epsi)) + (b3 & (int)(fabsf(z4.w - zi) < epsi));
    }
    if (p < N_TE) {
        atomicAdd(&cntY[c * N_TEP + p], ny);
        atomicAdd(&cntXY[c * N_TEP + p], nxy);
        atomicAdd(&cntYZ[c * N_TEP + p], nyz);
    }
}

// digamma + block-reduce into tes[c]. grid = (IB, C)
__global__ __launch_bounds__(256) void te_dig_kernel(
    const int* __restrict__ cntY, const int* __restrict__ cntXY,
    const int* __restrict__ cntYZ, float* __restrict__ tes) {
    __shared__ float wsum[4];
    const int c = blockIdx.y;
    const int p = blockIdx.x * 256 + threadIdx.x;
    float local = 0.0f;
    if (p < N_TE) {
        local = digammaf_dev((float)cntY[c * N_TEP + p])
              - digammaf_dev((float)cntXY[c * N_TEP + p])
              - digammaf_dev((float)cntYZ[c * N_TEP + p]);
    }
    #pragma unroll
    for (int m = 32; m >= 1; m >>= 1) local += __shfl_xor(local, m, 64);
    if ((threadIdx.x & 63) == 0) wsum[threadIdx.x >> 6] = local;
    __syncthreads();
    if (threadIdx.x == 0)
        atomicAdd(&tes[c], wsum[0] + wsum[1] + wsum[2] + wsum[3]);
}

template <int C>
__global__ void agg_kernel(const float* __restrict__ h, const int* __restrict__ ei,
                           const float* __restrict__ tes_accum, float half_scale,
                           float* __restrict__ sums) {
    int idx = blockIdx.x * blockDim.x + threadIdx.x;
    if (idx >= E_TOT * C) return;
    int e = idx / C, c = idx % C;
    float te = (-0.57721566490153286f + tes_accum[c] * (1.0f / (float)N_TE)) * half_scale;
    float xj = h[src_of(ei, e) * C + c];
    float m = 1.0f / (1.0f + expf(-te * xj));
    atomicAdd(&sums[dst_of(ei, e) * C + c], m);
}

__global__ void fin1_kernel(const float* __restrict__ sums, const float* __restrict__ cnt,
                            float* __restrict__ h1a) {
    int idx = blockIdx.x * blockDim.x + threadIdx.x;
    if (idx >= N_NODES * HID) return;
    int v = idx / HID;
    float val = sums[idx] / fmaxf(cnt[v], 1.0f);
    h1a[idx] = fmaxf(val, 0.0f);
}

__global__ void gemm2_kernel(const float* __restrict__ h1a, const float* __restrict__ W2,
                             const float* __restrict__ b2, float* __restrict__ h2) {
    int idx = blockIdx.x * blockDim.x + threadIdx.x;
    if (idx >= N_NODES * OUT_CH) return;
    int v = idx / OUT_CH, o = idx % OUT_CH;
    float s = b2[o];
    #pragma unroll
    for (int k = 0; k < HID; ++k) s += h1a[v * HID + k] * W2[o * HID + k];
    h2[idx] = s;
}

__global__ void fin2_kernel(const float* __restrict__ sums2, const float* __restrict__ cnt,
                            float* __restrict__ out) {
    int v = blockIdx.x * blockDim.x + threadIdx.x;
    if (v >= N_NODES) return;
    float c = fmaxf(cnt[v], 1.0f);
    float vals[OUT_CH];
    float mx = -INFINITY;
    #pragma unroll
    for (int o = 0; o < OUT_CH; ++o) {
        vals[o] = sums2[v * OUT_CH + o] / c;
        mx = fmaxf(mx, vals[o]);
    }
    float se = 0.0f;
    #pragma unroll
    for (int o = 0; o < OUT_CH; ++o) se += expf(vals[o] - mx);
    float lse = mx + logf(se);
    #pragma unroll
    for (int o = 0; o < OUT_CH; ++o) out[v * OUT_CH + o] = vals[o] - lse;
}

extern "C" void kernel_launch(void* const* d_in, const int* in_sizes, int n_in,
                              void* d_out, int out_size, void* d_ws, size_t ws_size,
                              hipStream_t stream) {
    const float* x  = (const float*)d_in[0];
    const int*   ei = (const int*)  d_in[1];
    const float* W1 = (const float*)d_in[2];
    const float* b1 = (const float*)d_in[3];
    const float* W2 = (const float*)d_in[4];
    const float* b2 = (const float*)d_in[5];
    float* out = (float*)d_out;

    float* w = (float*)d_ws;
    size_t o = 0;
    // ---- zeroed region (atomic accumulators) ----
    float* sums1 = w + o; o += N_NODES * HID;
    float* sums2 = w + o; o += N_NODES * OUT_CH;
    float* cdeg  = w + o; o += N_NODES;
    float* tes1  = w + o; o += 16;
    float* tes2  = w + o; o += 16;
    int* cY1  = (int*)(w + o); o += HID * N_TEP;
    int* cXY1 = (int*)(w + o); o += HID * N_TEP;
    int* cYZ1 = (int*)(w + o); o += HID * N_TEP;
    int* cY2  = (int*)(w + o); o += OUT_CH * N_TEP;
    int* cXY2 = (int*)(w + o); o += OUT_CH * N_TEP;
    int* cYZ2 = (int*)(w + o); o += OUT_CH * N_TEP;
    const size_t zero_elems = o;
    // ---- non-zeroed region (buffers shared between layers) ----
    float* h1      = w + o; o += N_NODES * HID;
    float* h1a     = w + o; o += N_NODES * HID;
    float* h2      = w + o; o += N_NODES * OUT_CH;
    float* ys_tmp  = w + o; o += HID * N_TEP;
    int*   idx_tmp = (int*)(w + o); o += HID * N_TEP;
    float* ys_srt  = w + o; o += HID * N_TEP;
    float* xs_srt  = w + o; o += HID * N_TEP;
    float* zs_srt  = w + o; o += HID * N_TEP;
    unsigned int* eps_u = (unsigned int*)(w + o); o += HID * N_TEP;
    int*   bstart  = (int*)(w + o); o += HID * (NBUCK + 1);
    float* meta    = w + o; o += 2 * HID;
    float* Mub     = w + o; o += HID * IB;
    float* M2      = w + o; o += HID * IB;

    hipMemsetAsync(d_ws, 0, zero_elems * sizeof(float), stream);

    gemm1_kernel<<<N_NODES, 256, 0, stream>>>(x, W1, b1, h1);
    deg_kernel<<<(E_TOT + 255) / 256, 256, 0, stream>>>(ei, cdeg);

    // ---- layer 1 ----
    sortA_kernel<<<HID, 1024, 0, stream>>>(h1, ei, HID, ys_tmp, idx_tmp, bstart, meta);
    sortB_kernel<<<dim3(IB, HID), 256, 0, stream>>>(h1, ei, HID, ys_tmp, idx_tmp,
                                                    bstart, meta, ys_srt, xs_srt, zs_srt);
    epsub_kernel<<<dim3(IB, HID), 256, 0, stream>>>(ys_srt, xs_srt, zs_srt, eps_u, Mub);
    te_eps_kernel<<<dim3(IB, NCH, HID), 256, 0, stream>>>(ys_srt, xs_srt, zs_srt, Mub, eps_u);
    blockmax_kernel<<<dim3(IB, HID), 256, 0, stream>>>(eps_u, M2);
    te_cnt_kernel<<<dim3(IB, NCH, HID), 256, 0, stream>>>(ys_srt, xs_srt, zs_srt, M2,
                                                          eps_u, cY1, cXY1, cYZ1);
    te_dig_kernel<<<dim3(IB, HID), 256, 0, stream>>>(cY1, cXY1, cYZ1, tes1);
    agg_kernel<HID><<<(E_TOT * HID + 255) / 256, 256, 0, stream>>>(h1, ei, tes1, 1.0f, sums1);
    fin1_kernel<<<(N_NODES * HID + 255) / 256, 256, 0, stream>>>(sums1, cdeg, h1a);

    // ---- layer 2 ----
    gemm2_kernel<<<(N_NODES * OUT_CH + 255) / 256, 256, 0, stream>>>(h1a, W2, b2, h2);
    sortA_kernel<<<OUT_CH, 1024, 0, stream>>>(h2, ei, OUT_CH, ys_tmp, idx_tmp, bstart, meta);
    sortB_kernel<<<dim3(IB, OUT_CH), 256, 0, stream>>>(h2, ei, OUT_CH, ys_tmp, idx_tmp,
                                                       bstart, meta, ys_srt, xs_srt, zs_srt);
    epsub_kernel<<<dim3(IB, OUT_CH), 256, 0, stream>>>(ys_srt, xs_srt, zs_srt, eps_u, Mub);
    te_eps_kernel<<<dim3(IB, NCH, OUT_CH), 256, 0, stream>>>(ys_srt, xs_srt, zs_srt, Mub, eps_u);
    blockmax_kernel<<<dim3(IB, OUT_CH), 256, 0, stream>>>(eps_u, M2);
    te_cnt_kernel<<<dim3(IB, NCH, OUT_CH), 256, 0, stream>>>(ys_srt, xs_srt, zs_srt, M2,
                                                             eps_u, cY2, cXY2, cYZ2);
    te_dig_kernel<<<dim3(IB, OUT_CH), 256, 0, stream>>>(cY2, cXY2, cYZ2, tes2);
    agg_kernel<OUT_CH><<<(E_TOT * OUT_CH + 255) / 256, 256, 0, stream>>>(h2, ei, tes2, 0.5f, sums2);
    fin2_kernel<<<(N_NODES + 255) / 256, 256, 0, stream>>>(sums2, cdeg, out);
}